// Round 3
// baseline (459.136 us; speedup 1.0000x reference)
//
#include <hip/hip_runtime.h>
#include <hip/hip_bf16.h>

// EGA layer (GAT-like, GLOBAL per-head softmax over edges) on MI355X.
// Pipeline:
//   packw -> MFMA split-GEMM (scores ONLY, no Wh store) -> edge score pass
//   -> finalize -> mark (compact passing edges + col flags)
//   -> whrows (fp32 Wh recompute for marked cols only) -> acc (scatter).
// GEMM on matrix cores via bf16x3 split (x=hi+lo, W=hi+lo, acc hi*hi+hi*lo+lo*hi,
// fp32 MFMA accumulate). Global softmax over 800K edges concentrates weight in
// O(100) edges; only those need Wh, so Wh (102 MB) is never streamed to HBM --
// it is recomputed in full fp32 for the few passing cols. Worst case (flat
// scores) degrades to a bounded full VALU GEMM: slow but correct.

#define N_NODES 50000
#define N_EDGES 800000
#define IN_DIM  256
#define OUT_DIM 64
#define HEADS   8
#define NCOL    (HEADS * OUT_DIM)   // 512
#define NBLK_RED 1024               // partial-reduction blocks for edge softmax
#define LN_W_EPS (-20.72326584f)    // ln(1e-9) skip threshold

typedef __attribute__((ext_vector_type(8))) short short8;   // 8 x bf16 (4 VGPRs)
typedef __attribute__((ext_vector_type(4))) float f32x4;

// RNE bf16 hi + trunc bf16 lo split of 2 floats -> packed u32s (lane-order j, j+1)
__device__ __forceinline__ void bf16_split2(float x0, float x1,
                                            unsigned& hi, unsigned& lo)
{
    unsigned u0 = __float_as_uint(x0), u1 = __float_as_uint(x1);
    unsigned r0 = u0 + 0x7FFFu + ((u0 >> 16) & 1u);   // RNE to bf16
    unsigned r1 = u1 + 0x7FFFu + ((u1 >> 16) & 1u);
    float h0 = __uint_as_float(r0 & 0xFFFF0000u);
    float h1 = __uint_as_float(r1 & 0xFFFF0000u);
    hi = (r0 >> 16) | (r1 & 0xFFFF0000u);
    unsigned l0 = __float_as_uint(x0 - h0);           // residual, trunc to bf16
    unsigned l1 = __float_as_uint(x1 - h1);
    lo = (l0 >> 16) | (l1 & 0xFFFF0000u);
}

// ---------------------------------------------------------------------------
// Pack W (fp32 [8][256][64]) into B-fragment layout, bf16 hi/lo.
// B fragment for mfma_16x16x32: lane l -> col=l&15, k=(l>>4)*8+j  => a wave's
// fragment read is 1KB contiguous. Total 512 KB, stays L2-resident.
// ---------------------------------------------------------------------------
__global__ __launch_bounds__(256) void packw_kernel(
    const float* __restrict__ W, short* __restrict__ wp)
{
    const int ct = blockIdx.x;            // 0..31
    const int h  = ct >> 2;               // head (4 col-tiles per head)
    #pragma unroll
    for (int it = 0; it < 2; ++it) {
        const int i  = threadIdx.x + it * 256;   // 512 items: (k8, c)
        const int k8 = i >> 4;
        const int c  = i & 15;
        const int o  = (ct & 3) * 16 + c;
        const float* src = W + (size_t)h * IN_DIM * OUT_DIM
                             + (size_t)k8 * 8 * OUT_DIM + o;
        unsigned hi[4], lo[4];
        #pragma unroll
        for (int p = 0; p < 4; ++p) {
            float x0 = src[(2 * p) * OUT_DIM];
            float x1 = src[(2 * p + 1) * OUT_DIM];
            bf16_split2(x0, x1, hi[p], lo[p]);
        }
        uint4 vh = make_uint4(hi[0], hi[1], hi[2], hi[3]);
        uint4 vl = make_uint4(lo[0], lo[1], lo[2], lo[3]);
        *(uint4*)(wp + (((size_t)(ct * 2 + 0) * 32 + k8) * 128) + c * 8) = vh;
        *(uint4*)(wp + (((size_t)(ct * 2 + 1) * 32 + k8) * 128) + c * 8) = vl;
    }
}

// ---------------------------------------------------------------------------
// MFMA GEMM, SCORES ONLY: computes Wh in-register, emits s_src/s_dst.
// 256 threads = 4 waves; grid = 782 panels x 2 head-halves; wave w handles
// head hh*4+w over the block's 64-row panel (4x4 frags of 16x16x32).
// x panel staged once to LDS as bf16 hi/lo, XOR-swizzled. Full A+B register
// double-buffer (launch_bounds(256,2) -> 256-reg budget; r2's (512,4) starved
// VGPRs to 64 and serialized the loop). Scores staged in LDS, stored as
// coalesced float4 (r2's scalar stores cost ~50 MB of RFO traffic).
// ---------------------------------------------------------------------------
__global__ __launch_bounds__(256, 2) void gemm_kernel(
    const float* __restrict__ x, const short* __restrict__ wp,
    const float* __restrict__ b, const float* __restrict__ a,
    float* __restrict__ s_src, float* __restrict__ s_dst)
{
    // [mi(4)][s(2)][k8(32)][r(16)][j(8)] halfs, 16B chunk index XOR-swizzled
    __shared__ __align__(16) short As[32768];   // 64 KB
    __shared__ __align__(16) float s_tmp[2][64][4];  // 2 KB score staging

    const int pid  = blockIdx.x >> 1;
    const int hh   = blockIdx.x & 1;
    const int row0 = pid * 64;
    const int tid  = threadIdx.x;
    const int lane = tid & 63;
    const int w    = tid >> 6;            // wave 0..3
    const int head = hh * 4 + w;
    const int r16  = lane & 15;
    const int kq   = lane >> 4;

    // ---- prefetch B[ks=0] before the fill: L2 latency hides under fill ----
    const short* pB = wp + (size_t)kq * 128 + (size_t)r16 * 8;
    #define LD_B(ni, s, ks) \
        (*(const short8*)(pB + ((((size_t)(head * 4 + (ni)) * 2 + (s)) * 32 + 4 * (ks)) * 128)))
    short8 Bh[2][4], Bl[2][4];
    #pragma unroll
    for (int ni = 0; ni < 4; ++ni) { Bh[0][ni] = LD_B(ni, 0, 0); Bl[0][ni] = LD_B(ni, 1, 0); }

    // ---- fill LDS: x panel -> bf16 hi/lo fragment layout (once per block) ----
    #pragma unroll
    for (int q = 0; q < 8; ++q) {
        const int item = q * 256 + tid;           // 2048 items: (row, kc)
        const int row  = item >> 5;               // 0..63
        const int kc   = item & 31;               // K-chunk of 8
        const int grow = row0 + row;
        f32x4 v0 = {0.f, 0.f, 0.f, 0.f}, v1 = {0.f, 0.f, 0.f, 0.f};
        if (grow < N_NODES) {
            v0 = *(const f32x4*)(x + (size_t)grow * IN_DIM + kc * 8);
            v1 = *(const f32x4*)(x + (size_t)grow * IN_DIM + kc * 8 + 4);
        }
        unsigned hi[4], lo[4];
        bf16_split2(v0.x, v0.y, hi[0], lo[0]);
        bf16_split2(v0.z, v0.w, hi[1], lo[1]);
        bf16_split2(v1.x, v1.y, hi[2], lo[2]);
        bf16_split2(v1.z, v1.w, hi[3], lo[3]);
        const int mi  = row >> 4, rr = row & 15;
        const int swz = rr ^ (kc & 15);
        uint4 vh = make_uint4(hi[0], hi[1], hi[2], hi[3]);
        uint4 vl = make_uint4(lo[0], lo[1], lo[2], lo[3]);
        *(uint4*)((char*)As + ((((mi * 2 + 0) * 32 + kc) * 16 + swz) * 16)) = vh;
        *(uint4*)((char*)As + ((((mi * 2 + 1) * 32 + kc) * 16 + swz) * 16)) = vl;
    }
    __syncthreads();

    // ---- K-loop (verified r1/r2 structure) ----
    f32x4 acc[4][4] = {};

    #define LD_A(mi, s, ks) \
        (*(const short8*)((const char*)As + \
            (((((mi) * 2 + (s)) * 32 + (4 * (ks) + kq)) * 16 + \
              (r16 ^ ((4 * ((ks) & 3) + kq)))) * 16)))

    short8 Ah[2][4], Al[2][4];
    #pragma unroll
    for (int mi = 0; mi < 4; ++mi) { Ah[0][mi] = LD_A(mi, 0, 0); Al[0][mi] = LD_A(mi, 1, 0); }

    #pragma unroll
    for (int ks = 0; ks < 8; ++ks) {
        const int cur = ks & 1, nxt = cur ^ 1;
        if (ks < 7) {
            #pragma unroll
            for (int ni = 0; ni < 4; ++ni) {
                Bh[nxt][ni] = LD_B(ni, 0, ks + 1);
                Bl[nxt][ni] = LD_B(ni, 1, ks + 1);
            }
            #pragma unroll
            for (int mi = 0; mi < 4; ++mi) {
                Ah[nxt][mi] = LD_A(mi, 0, ks + 1);
                Al[nxt][mi] = LD_A(mi, 1, ks + 1);
            }
        }
        #pragma unroll
        for (int mi = 0; mi < 4; ++mi)
            #pragma unroll
            for (int ni = 0; ni < 4; ++ni) {
                acc[mi][ni] = __builtin_amdgcn_mfma_f32_16x16x32_bf16(
                    Ah[cur][mi], Bh[cur][ni], acc[mi][ni], 0, 0, 0);
                acc[mi][ni] = __builtin_amdgcn_mfma_f32_16x16x32_bf16(
                    Ah[cur][mi], Bl[cur][ni], acc[mi][ni], 0, 0, 0);
                acc[mi][ni] = __builtin_amdgcn_mfma_f32_16x16x32_bf16(
                    Al[cur][mi], Bh[cur][ni], acc[mi][ni], 0, 0, 0);
            }
    }
    #undef LD_A
    #undef LD_B

    // ---- epilogue: fused score dot-products only (no Wh store) ----
    // C layout (verified): col = lane&15, row = (lane>>4)*4 + reg
    const int n0 = head * 64;
    float bias[4], avs[4], avd[4];
    #pragma unroll
    for (int ni = 0; ni < 4; ++ni) {
        bias[ni] = b[n0 + ni * 16 + r16];
        avs[ni]  = a[head * 128 + ni * 16 + r16];
        avd[ni]  = a[head * 128 + 64 + ni * 16 + r16];
    }
    #pragma unroll
    for (int mi = 0; mi < 4; ++mi) {
        #pragma unroll
        for (int reg = 0; reg < 4; ++reg) {
            float ps = 0.f, pd = 0.f;
            #pragma unroll
            for (int ni = 0; ni < 4; ++ni) {
                const float v = acc[mi][ni][reg] + bias[ni];
                ps += v * avs[ni];
                pd += v * avd[ni];
            }
            ps += __shfl_xor(ps, 1); pd += __shfl_xor(pd, 1);
            ps += __shfl_xor(ps, 2); pd += __shfl_xor(pd, 2);
            ps += __shfl_xor(ps, 4); pd += __shfl_xor(pd, 4);
            ps += __shfl_xor(ps, 8); pd += __shfl_xor(pd, 8);
            if (r16 == 0) {
                const int rloc = mi * 16 + kq * 4 + reg;
                s_tmp[0][rloc][w] = ps;
                s_tmp[1][rloc][w] = pd;
            }
        }
    }
    __syncthreads();
    if (tid < 128) {
        const int r = row0 + (tid & 63);
        if (r < N_NODES) {
            float* dst = (tid < 64) ? s_src : s_dst;
            *(float4*)(dst + (size_t)r * 8 + hh * 4) =
                *(const float4*)&s_tmp[tid >> 6][tid & 63][0];
        }
    }
}

// ---------------------------------------------------------------------------
// Edge score pass: lane-pair split (even lane: heads 0-3, odd: heads 4-7).
// Per edge-pair: ONE float4 gather per table per lane + half the per-lane
// online-softmax VALU. Writes per-block online (m,l) partials.
// ---------------------------------------------------------------------------
__global__ __launch_bounds__(256) void edge_score_kernel(
    const int* __restrict__ ei, const float* __restrict__ s_src,
    const float* __restrict__ s_dst, float* __restrict__ partial)
{
    const int tid  = threadIdx.x;
    const int half = tid & 1;            // heads half*4 .. half*4+3

    float m[4], l[4];
    #pragma unroll
    for (int i = 0; i < 4; ++i) { m[i] = -1e30f; l[i] = 0.f; }

    for (int p = blockIdx.x * 128 + (tid >> 1); p < N_EDGES; p += gridDim.x * 128) {
        const int row = ei[p];
        const int col = ei[N_EDGES + p];
        const f32x4 s = *(const f32x4*)(s_src + row * 8 + half * 4);
        const f32x4 d = *(const f32x4*)(s_dst + col * 8 + half * 4);
        #pragma unroll
        for (int i = 0; i < 4; ++i) {
            float v = s[i] + d[i];
            const float t = v > 0.f ? v : 0.01f * v;  // leaky_relu 0.01
            const float mn = fmaxf(m[i], t);
            l[i] = l[i] * __expf(m[i] - mn) + __expf(t - mn);
            m[i] = mn;
        }
    }

    // block reduce; parity-preserving strides keep head mapping intact
    __shared__ float red[8][256];
    #pragma unroll
    for (int i = 0; i < 4; ++i) { red[i][tid] = m[i]; red[4 + i][tid] = l[i]; }
    __syncthreads();
    for (int s = 128; s >= 2; s >>= 1) {
        if (tid < s) {
            #pragma unroll
            for (int i = 0; i < 4; ++i) {
                const float mo = red[i][tid + s], lo = red[4 + i][tid + s];
                const float mm = red[i][tid],     ll = red[4 + i][tid];
                const float mn = fmaxf(mm, mo);
                red[4 + i][tid] = ll * __expf(mm - mn) + lo * __expf(mo - mn);
                red[i][tid]     = mn;
            }
        }
        __syncthreads();
    }
    if (tid < 2) {
        #pragma unroll
        for (int i = 0; i < 4; ++i) {
            partial[blockIdx.x * 16 + tid * 4 + i]     = red[i][tid];
            partial[blockIdx.x * 16 + 8 + tid * 4 + i] = red[4 + i][tid];
        }
    }
}

// ---------------------------------------------------------------------------
// Merge partials. coef[h]=M_h, coef[8+h]=g_h/L_h, coef[16+h]=skip cutoff.
// ---------------------------------------------------------------------------
__global__ __launch_bounds__(256) void finalize_kernel(
    const float* __restrict__ partial, const float* __restrict__ gate,
    float* __restrict__ coef, int nblk)
{
    const int t = threadIdx.x;
    const int h = t & 7;
    const int j = t >> 3;                 // 0..31
    float m = -1e30f, l = 0.f;
    for (int bk = j; bk < nblk; bk += 32) {
        const float mb = partial[bk * 16 + h];
        const float lb = partial[bk * 16 + 8 + h];
        const float mn = fmaxf(m, mb);
        l = l * __expf(m - mn) + lb * __expf(mb - mn);
        m = mn;
    }
    __shared__ float rm[256], rl[256];
    rm[t] = m; rl[t] = l;
    __syncthreads();
    for (int s = 128; s >= 8; s >>= 1) {
        if (t < s) {
            const float mo = rm[t + s], lo = rl[t + s];
            const float mn = fmaxf(rm[t], mo);
            rl[t] = rl[t] * __expf(rm[t] - mn) + lo * __expf(mo - mn);
            rm[t] = mn;
        }
        __syncthreads();
    }
    if (t < 8) {
        float gm = gate[0];
        for (int i = 1; i < 8; ++i) gm = fmaxf(gm, gate[i]);
        float gs = 0.f;
        for (int i = 0; i < 8; ++i) gs += __expf(gate[i] - gm);
        const float g = __expf(gate[t] - gm) / gs;
        const float C = g / rl[t];
        coef[t]      = rm[t];
        coef[8 + t]  = C;
        coef[16 + t] = rm[t] + LN_W_EPS - __logf(C);   // t >= cut  <=>  w >= eps
    }
}

// ---------------------------------------------------------------------------
// Mark: recompute t per edge from score gathers, threshold, append passing
// edge ids to elist (wave-aggregated atomic) and flag their cols.
// ---------------------------------------------------------------------------
__global__ __launch_bounds__(256) void mark_kernel(
    const int* __restrict__ ei, const float* __restrict__ s_src,
    const float* __restrict__ s_dst, const float* __restrict__ coef,
    int* __restrict__ elist, int* __restrict__ colflag, int* __restrict__ ecount)
{
    __shared__ float cCut[8];
    if (threadIdx.x < 8) cCut[threadIdx.x] = coef[16 + threadIdx.x];
    __syncthreads();

    const int e = blockIdx.x * 256 + threadIdx.x;
    bool pass = false;
    int col = 0;
    if (e < N_EDGES) {
        const int row = ei[e];
        col = ei[N_EDGES + e];
        const float4 s0 = *(const float4*)(s_src + row * 8);
        const float4 s1 = *(const float4*)(s_src + row * 8 + 4);
        const float4 d0 = *(const float4*)(s_dst + col * 8);
        const float4 d1 = *(const float4*)(s_dst + col * 8 + 4);
        float t[8] = { s0.x + d0.x, s0.y + d0.y, s0.z + d0.z, s0.w + d0.w,
                       s1.x + d1.x, s1.y + d1.y, s1.z + d1.z, s1.w + d1.w };
        #pragma unroll
        for (int h = 0; h < 8; ++h) {
            t[h] = t[h] > 0.f ? t[h] : 0.01f * t[h];
            pass |= (t[h] >= cCut[h]);
        }
    }

    const unsigned long long mask = __ballot(pass);
    if (mask) {
        const int lane   = threadIdx.x & 63;
        const int leader = (int)__builtin_ctzll(mask);
        int base = 0;
        if (lane == leader) base = atomicAdd(ecount, (int)__popcll(mask));
        base = __shfl(base, leader);
        if (pass) {
            const int rank = (int)__popcll(mask & ((1ULL << lane) - 1ULL));
            elist[base + rank] = e;
            colflag[col] = 1;            // benign race: all writers store 1
        }
    }
}

// ---------------------------------------------------------------------------
// Wh recompute, fp32 full precision, ONLY for flagged cols. Block handles 64
// nodes; wave per node: lane=(hq,oq), f32x4 over o, x row staged in LDS.
// Common case: ~100 flagged nodes total. Worst case: full VALU GEMM, bounded.
// ---------------------------------------------------------------------------
__global__ __launch_bounds__(256) void whrows_kernel(
    const float* __restrict__ x, const float* __restrict__ W,
    const float* __restrict__ b, const int* __restrict__ colflag,
    float* __restrict__ Wh)
{
    __shared__ __align__(16) float xr[4][256];
    const int w    = threadIdx.x >> 6;
    const int lane = threadIdx.x & 63;
    const int n0   = blockIdx.x * 64;

    for (int i = w; i < 64; i += 4) {
        const int n = n0 + i;
        if (n >= N_NODES) break;
        if (colflag[n] == 0) continue;

        *(f32x4*)&xr[w][lane * 4] = *(const f32x4*)(x + (size_t)n * IN_DIM + lane * 4);
        // same-wave ds_write -> ds_read: compiler inserts lgkmcnt wait
        const int hq = lane >> 4, oq = lane & 15;
        f32x4 acc0 = {0.f, 0.f, 0.f, 0.f}, acc1 = {0.f, 0.f, 0.f, 0.f};
        for (int k = 0; k < IN_DIM; ++k) {
            const float xk = xr[w][k];
            acc0 += xk * *(const f32x4*)(W + ((size_t)hq * IN_DIM + k) * OUT_DIM + oq * 4);
            acc1 += xk * *(const f32x4*)(W + ((size_t)(hq + 4) * IN_DIM + k) * OUT_DIM + oq * 4);
        }
        acc0 += *(const f32x4*)(b + hq * OUT_DIM + oq * 4);
        acc1 += *(const f32x4*)(b + (hq + 4) * OUT_DIM + oq * 4);
        *(f32x4*)(Wh + (size_t)n * NCOL + hq * OUT_DIM + oq * 4)       = acc0;
        *(f32x4*)(Wh + (size_t)n * NCOL + (hq + 4) * OUT_DIM + oq * 4) = acc1;
    }
}

// ---------------------------------------------------------------------------
// Accumulate: iterate the compact passing-edge list; recompute w[8] from
// score gathers; wave-cooperative gather of (fp32) Wh[col]; atomicAdd out.
// ---------------------------------------------------------------------------
__global__ __launch_bounds__(256) void acc_kernel(
    const int* __restrict__ ei, const float* __restrict__ s_src,
    const float* __restrict__ s_dst, const float* __restrict__ Wh,
    const float* __restrict__ coef, const int* __restrict__ elist,
    const int* __restrict__ ecount, float* __restrict__ out)
{
    __shared__ float cM[8], cC[8];
    if (threadIdx.x < 8)       cM[threadIdx.x]     = coef[threadIdx.x];
    else if (threadIdx.x < 16) cC[threadIdx.x - 8] = coef[threadIdx.x];
    __syncthreads();

    const int n    = *ecount;
    const int lane = threadIdx.x & 63;

    for (int i = blockIdx.x * 256 + threadIdx.x; ; i += gridDim.x * 256) {
        const bool has = i < n;
        if (!__any(has)) break;

        int row = 0, col = 0;
        float wgt[8];
        if (has) {
            const int e = elist[i];
            row = ei[e];
            col = ei[N_EDGES + e];
            const float4 s0 = *(const float4*)(s_src + row * 8);
            const float4 s1 = *(const float4*)(s_src + row * 8 + 4);
            const float4 d0 = *(const float4*)(s_dst + col * 8);
            const float4 d1 = *(const float4*)(s_dst + col * 8 + 4);
            float t[8] = { s0.x + d0.x, s0.y + d0.y, s0.z + d0.z, s0.w + d0.w,
                           s1.x + d1.x, s1.y + d1.y, s1.z + d1.z, s1.w + d1.w };
            #pragma unroll
            for (int h = 0; h < 8; ++h) {
                t[h] = t[h] > 0.f ? t[h] : 0.01f * t[h];
                wgt[h] = __expf(t[h] - cM[h]) * cC[h];
            }
        }

        unsigned long long mask = __ballot(has);
        while (mask) {
            const int src = (int)__builtin_ctzll(mask);
            mask &= mask - 1;
            const int rb = __shfl(row, src);
            const int cb = __shfl(col, src);
            const float* wc = Wh + (size_t)cb * NCOL + lane;   // plain layout
            float acc = 0.f;
            #pragma unroll
            for (int h = 0; h < 8; ++h)
                acc += __shfl(wgt[h], src) * wc[h * 64];
            atomicAdd(out + (size_t)rb * OUT_DIM + lane, acc);
        }
    }
}

// ---------------------------------------------------------------------------
extern "C" void kernel_launch(void* const* d_in, const int* in_sizes, int n_in,
                              void* d_out, int out_size, void* d_ws, size_t ws_size,
                              hipStream_t stream)
{
    const float* x    = (const float*)d_in[0];
    const int*   ei   = (const int*)  d_in[1];
    const float* W    = (const float*)d_in[2];
    const float* b    = (const float*)d_in[3];
    const float* a    = (const float*)d_in[4];
    const float* gate = (const float*)d_in[5];
    float* out = (float*)d_out;

    // workspace (floats): Wh | s_src | s_dst | partial | coef | wp | elist |
    //                     colflag+ecount   (~110 MB)
    float* ws      = (float*)d_ws;
    float* Wh      = ws;
    float* s_src   = Wh    + (size_t)N_NODES * NCOL;
    float* s_dst   = s_src + (size_t)N_NODES * HEADS;
    float* partial = s_dst + (size_t)N_NODES * HEADS;
    float* coef    = partial + (size_t)NBLK_RED * 16;
    short* wp      = (short*)(coef + 32);              // 512 KB, 16B-aligned
    int*   elist   = (int*)(wp + 262144);              // 800K ints
    int*   colflag = elist + N_EDGES;                  // 50K ints
    int*   ecount  = colflag + N_NODES;                // 1 int

    hipMemsetAsync(d_out, 0, (size_t)N_NODES * OUT_DIM * sizeof(float), stream);
    hipMemsetAsync(colflag, 0, (size_t)(N_NODES + 1) * sizeof(int), stream);

    packw_kernel<<<32, 256, 0, stream>>>(W, wp);

    gemm_kernel<<<((N_NODES + 63) / 64) * 2, 256, 0, stream>>>(
        x, wp, b, a, s_src, s_dst);

    edge_score_kernel<<<NBLK_RED, 256, 0, stream>>>(ei, s_src, s_dst, partial);

    finalize_kernel<<<1, 256, 0, stream>>>(partial, gate, coef, NBLK_RED);

    mark_kernel<<<(N_EDGES + 255) / 256, 256, 0, stream>>>(
        ei, s_src, s_dst, coef, elist, colflag, ecount);

    whrows_kernel<<<(N_NODES + 63) / 64, 256, 0, stream>>>(x, W, b, colflag, Wh);

    acc_kernel<<<256, 256, 0, stream>>>(
        ei, s_src, s_dst, Wh, coef, elist, ecount, out);
}

// Round 5
// 367.277 us; speedup vs baseline: 1.2501x; 1.2501x over previous
//
#include <hip/hip_runtime.h>
#include <hip/hip_bf16.h>

// EGA layer (GAT-like, GLOBAL per-head softmax over edges) on MI355X.
// Pipeline:
//   packw -> MFMA split-GEMM (scores ONLY, no Wh store) -> edge score pass
//   -> finalize -> mark (compact passing edges + passing-col node list)
//   -> whrows (MFMA bf16x3 Wh recompute for marked cols only) -> acc (scatter).
// GEMM on matrix cores via bf16x3 split (x=hi+lo, W=hi+lo, acc hi*hi+hi*lo+lo*hi,
// fp32 MFMA accumulate). Global softmax over 800K edges concentrates weight in
// O(10^3..10^4) edges; only those need Wh, so Wh (102 MB) is never streamed to
// HBM -- it is recomputed (same MFMA path) for the ~6K marked cols. Worst case
// (flat scores) degrades to one extra full MFMA GEMM: bounded and correct.

#define N_NODES 50000
#define N_EDGES 800000
#define IN_DIM  256
#define OUT_DIM 64
#define HEADS   8
#define NCOL    (HEADS * OUT_DIM)   // 512
#define NBLK_RED 1024               // partial-reduction blocks for edge softmax
#define LN_W_EPS (-20.72326584f)    // ln(1e-9) skip threshold

typedef __attribute__((ext_vector_type(8))) short short8;   // 8 x bf16 (4 VGPRs)
typedef __attribute__((ext_vector_type(4))) float f32x4;

// RNE bf16 hi + trunc bf16 lo split of 2 floats -> packed u32s (lane-order j, j+1)
__device__ __forceinline__ void bf16_split2(float x0, float x1,
                                            unsigned& hi, unsigned& lo)
{
    unsigned u0 = __float_as_uint(x0), u1 = __float_as_uint(x1);
    unsigned r0 = u0 + 0x7FFFu + ((u0 >> 16) & 1u);   // RNE to bf16
    unsigned r1 = u1 + 0x7FFFu + ((u1 >> 16) & 1u);
    float h0 = __uint_as_float(r0 & 0xFFFF0000u);
    float h1 = __uint_as_float(r1 & 0xFFFF0000u);
    hi = (r0 >> 16) | (r1 & 0xFFFF0000u);
    unsigned l0 = __float_as_uint(x0 - h0);           // residual, trunc to bf16
    unsigned l1 = __float_as_uint(x1 - h1);
    lo = (l0 >> 16) | (l1 & 0xFFFF0000u);
}

// ---------------------------------------------------------------------------
// Pack W (fp32 [8][256][64]) into B-fragment layout, bf16 hi/lo.
// B fragment for mfma_16x16x32: lane l -> col=l&15, k=(l>>4)*8+j  => a wave's
// fragment read is 1KB contiguous. Total 512 KB, stays L2-resident.
// ---------------------------------------------------------------------------
__global__ __launch_bounds__(256) void packw_kernel(
    const float* __restrict__ W, short* __restrict__ wp)
{
    const int ct = blockIdx.x;            // 0..31
    const int h  = ct >> 2;               // head (4 col-tiles per head)
    #pragma unroll
    for (int it = 0; it < 2; ++it) {
        const int i  = threadIdx.x + it * 256;   // 512 items: (k8, c)
        const int k8 = i >> 4;
        const int c  = i & 15;
        const int o  = (ct & 3) * 16 + c;
        const float* src = W + (size_t)h * IN_DIM * OUT_DIM
                             + (size_t)k8 * 8 * OUT_DIM + o;
        unsigned hi[4], lo[4];
        #pragma unroll
        for (int p = 0; p < 4; ++p) {
            float x0 = src[(2 * p) * OUT_DIM];
            float x1 = src[(2 * p + 1) * OUT_DIM];
            bf16_split2(x0, x1, hi[p], lo[p]);
        }
        uint4 vh = make_uint4(hi[0], hi[1], hi[2], hi[3]);
        uint4 vl = make_uint4(lo[0], lo[1], lo[2], lo[3]);
        *(uint4*)(wp + (((size_t)(ct * 2 + 0) * 32 + k8) * 128) + c * 8) = vh;
        *(uint4*)(wp + (((size_t)(ct * 2 + 1) * 32 + k8) * 128) + c * 8) = vl;
    }
}

// ---------------------------------------------------------------------------
// MFMA GEMM, SCORES ONLY. 512 threads = 8 waves; wave == head; one 64-row
// x-panel staged ONCE per block (serves all 8 heads), bf16 hi/lo, XOR-swizzle.
// __launch_bounds__(512,2): 256-reg budget (r2's (512,4) starved VGPRs to 64
// and serialized the K-loop) AND 2 blocks/CU = 4 waves/SIMD (r1's (256,2) ran
// at 2 waves/SIMD, latency-exposed). Scores staged in LDS, float4 stores.
// ---------------------------------------------------------------------------
__global__ __launch_bounds__(512, 2) void gemm_kernel(
    const float* __restrict__ x, const short* __restrict__ wp,
    const float* __restrict__ b, const float* __restrict__ a,
    float* __restrict__ s_src, float* __restrict__ s_dst)
{
    // [mi(4)][s(2)][k8(32)][r(16)][j(8)] halfs, 16B chunk index XOR-swizzled
    __shared__ __align__(16) short As[32768];        // 64 KB
    __shared__ __align__(16) float s_tmp[2][64][8];  // 4 KB score staging

    const int row0 = blockIdx.x * 64;
    const int tid  = threadIdx.x;
    const int lane = tid & 63;
    const int head = tid >> 6;            // wave == head 0..7
    const int r16  = lane & 15;
    const int kq   = lane >> 4;

    // ---- prefetch B[ks=0] before the fill: L2 latency hides under fill ----
    const short* pB = wp + (size_t)kq * 128 + (size_t)r16 * 8;
    #define LD_B(ni, s, ks) \
        (*(const short8*)(pB + ((((size_t)(head * 4 + (ni)) * 2 + (s)) * 32 + 4 * (ks)) * 128)))
    short8 Bh[2][4], Bl[2][4];
    #pragma unroll
    for (int ni = 0; ni < 4; ++ni) { Bh[0][ni] = LD_B(ni, 0, 0); Bl[0][ni] = LD_B(ni, 1, 0); }

    // ---- fill LDS: x panel -> bf16 hi/lo fragment layout (once per block) ----
    #pragma unroll
    for (int q = 0; q < 4; ++q) {
        const int item = q * 512 + tid;           // 2048 items: (row, kc)
        const int row  = item >> 5;               // 0..63
        const int kc   = item & 31;               // K-chunk of 8
        const int grow = row0 + row;
        f32x4 v0 = {0.f, 0.f, 0.f, 0.f}, v1 = {0.f, 0.f, 0.f, 0.f};
        if (grow < N_NODES) {
            v0 = *(const f32x4*)(x + (size_t)grow * IN_DIM + kc * 8);
            v1 = *(const f32x4*)(x + (size_t)grow * IN_DIM + kc * 8 + 4);
        }
        unsigned hi[4], lo[4];
        bf16_split2(v0.x, v0.y, hi[0], lo[0]);
        bf16_split2(v0.z, v0.w, hi[1], lo[1]);
        bf16_split2(v1.x, v1.y, hi[2], lo[2]);
        bf16_split2(v1.z, v1.w, hi[3], lo[3]);
        const int mi  = row >> 4, rr = row & 15;
        const int swz = rr ^ (kc & 15);
        uint4 vh = make_uint4(hi[0], hi[1], hi[2], hi[3]);
        uint4 vl = make_uint4(lo[0], lo[1], lo[2], lo[3]);
        *(uint4*)((char*)As + ((((mi * 2 + 0) * 32 + kc) * 16 + swz) * 16)) = vh;
        *(uint4*)((char*)As + ((((mi * 2 + 1) * 32 + kc) * 16 + swz) * 16)) = vl;
    }
    __syncthreads();

    // ---- K-loop (verified r1/r2 structure) ----
    f32x4 acc[4][4] = {};

    #define LD_A(mi, s, ks) \
        (*(const short8*)((const char*)As + \
            (((((mi) * 2 + (s)) * 32 + (4 * (ks) + kq)) * 16 + \
              (r16 ^ ((4 * ((ks) & 3) + kq)))) * 16)))

    short8 Ah[2][4], Al[2][4];
    #pragma unroll
    for (int mi = 0; mi < 4; ++mi) { Ah[0][mi] = LD_A(mi, 0, 0); Al[0][mi] = LD_A(mi, 1, 0); }

    #pragma unroll
    for (int ks = 0; ks < 8; ++ks) {
        const int cur = ks & 1, nxt = cur ^ 1;
        if (ks < 7) {
            #pragma unroll
            for (int ni = 0; ni < 4; ++ni) {
                Bh[nxt][ni] = LD_B(ni, 0, ks + 1);
                Bl[nxt][ni] = LD_B(ni, 1, ks + 1);
            }
            #pragma unroll
            for (int mi = 0; mi < 4; ++mi) {
                Ah[nxt][mi] = LD_A(mi, 0, ks + 1);
                Al[nxt][mi] = LD_A(mi, 1, ks + 1);
            }
        }
        #pragma unroll
        for (int mi = 0; mi < 4; ++mi)
            #pragma unroll
            for (int ni = 0; ni < 4; ++ni) {
                acc[mi][ni] = __builtin_amdgcn_mfma_f32_16x16x32_bf16(
                    Ah[cur][mi], Bh[cur][ni], acc[mi][ni], 0, 0, 0);
                acc[mi][ni] = __builtin_amdgcn_mfma_f32_16x16x32_bf16(
                    Ah[cur][mi], Bl[cur][ni], acc[mi][ni], 0, 0, 0);
                acc[mi][ni] = __builtin_amdgcn_mfma_f32_16x16x32_bf16(
                    Al[cur][mi], Bh[cur][ni], acc[mi][ni], 0, 0, 0);
            }
    }
    #undef LD_A
    #undef LD_B

    // ---- epilogue: fused score dot-products only (no Wh store) ----
    // C layout (verified): col = lane&15, row = (lane>>4)*4 + reg
    const int n0 = head * 64;
    float bias[4], avs[4], avd[4];
    #pragma unroll
    for (int ni = 0; ni < 4; ++ni) {
        bias[ni] = b[n0 + ni * 16 + r16];
        avs[ni]  = a[head * 128 + ni * 16 + r16];
        avd[ni]  = a[head * 128 + 64 + ni * 16 + r16];
    }
    #pragma unroll
    for (int mi = 0; mi < 4; ++mi) {
        #pragma unroll
        for (int reg = 0; reg < 4; ++reg) {
            float ps = 0.f, pd = 0.f;
            #pragma unroll
            for (int ni = 0; ni < 4; ++ni) {
                const float v = acc[mi][ni][reg] + bias[ni];
                ps += v * avs[ni];
                pd += v * avd[ni];
            }
            ps += __shfl_xor(ps, 1); pd += __shfl_xor(pd, 1);
            ps += __shfl_xor(ps, 2); pd += __shfl_xor(pd, 2);
            ps += __shfl_xor(ps, 4); pd += __shfl_xor(pd, 4);
            ps += __shfl_xor(ps, 8); pd += __shfl_xor(pd, 8);
            if (r16 == 0) {
                const int rloc = mi * 16 + kq * 4 + reg;
                s_tmp[0][rloc][head] = ps;
                s_tmp[1][rloc][head] = pd;
            }
        }
    }
    __syncthreads();
    if (tid < 256) {
        const int r   = tid & 63;
        const int sel = tid >> 6;            // 0..3: src-lo, src-hi, dst-lo, dst-hi
        const int gr  = row0 + r;
        if (gr < N_NODES) {
            float* dst = (sel < 2) ? s_src : s_dst;
            *(float4*)(dst + (size_t)gr * 8 + (sel & 1) * 4) =
                *(const float4*)&s_tmp[sel >> 1][r][(sel & 1) * 4];
        }
    }
}

// ---------------------------------------------------------------------------
// Edge score pass: lane-pair split (even lane: heads 0-3, odd: heads 4-7).
// Per edge-pair: ONE float4 gather per table per lane + half the per-lane
// online-softmax VALU. Writes per-block online (m,l) partials.
// ---------------------------------------------------------------------------
__global__ __launch_bounds__(256) void edge_score_kernel(
    const int* __restrict__ ei, const float* __restrict__ s_src,
    const float* __restrict__ s_dst, float* __restrict__ partial)
{
    const int tid  = threadIdx.x;
    const int half = tid & 1;            // heads half*4 .. half*4+3

    float m[4], l[4];
    #pragma unroll
    for (int i = 0; i < 4; ++i) { m[i] = -1e30f; l[i] = 0.f; }

    for (int p = blockIdx.x * 128 + (tid >> 1); p < N_EDGES; p += gridDim.x * 128) {
        const int row = ei[p];
        const int col = ei[N_EDGES + p];
        const f32x4 s = *(const f32x4*)(s_src + row * 8 + half * 4);
        const f32x4 d = *(const f32x4*)(s_dst + col * 8 + half * 4);
        #pragma unroll
        for (int i = 0; i < 4; ++i) {
            float v = s[i] + d[i];
            const float t = v > 0.f ? v : 0.01f * v;  // leaky_relu 0.01
            const float mn = fmaxf(m[i], t);
            l[i] = l[i] * __expf(m[i] - mn) + __expf(t - mn);
            m[i] = mn;
        }
    }

    // block reduce; parity-preserving strides keep head mapping intact
    __shared__ float red[8][256];
    #pragma unroll
    for (int i = 0; i < 4; ++i) { red[i][tid] = m[i]; red[4 + i][tid] = l[i]; }
    __syncthreads();
    for (int s = 128; s >= 2; s >>= 1) {
        if (tid < s) {
            #pragma unroll
            for (int i = 0; i < 4; ++i) {
                const float mo = red[i][tid + s], lo = red[4 + i][tid + s];
                const float mm = red[i][tid],     ll = red[4 + i][tid];
                const float mn = fmaxf(mm, mo);
                red[4 + i][tid] = ll * __expf(mm - mn) + lo * __expf(mo - mn);
                red[i][tid]     = mn;
            }
        }
        __syncthreads();
    }
    if (tid < 2) {
        #pragma unroll
        for (int i = 0; i < 4; ++i) {
            partial[blockIdx.x * 16 + tid * 4 + i]     = red[i][tid];
            partial[blockIdx.x * 16 + 8 + tid * 4 + i] = red[4 + i][tid];
        }
    }
}

// ---------------------------------------------------------------------------
// Merge partials. coef[h]=M_h, coef[8+h]=g_h/L_h, coef[16+h]=skip cutoff.
// ---------------------------------------------------------------------------
__global__ __launch_bounds__(256) void finalize_kernel(
    const float* __restrict__ partial, const float* __restrict__ gate,
    float* __restrict__ coef, int nblk)
{
    const int t = threadIdx.x;
    const int h = t & 7;
    const int j = t >> 3;                 // 0..31
    float m = -1e30f, l = 0.f;
    for (int bk = j; bk < nblk; bk += 32) {
        const float mb = partial[bk * 16 + h];
        const float lb = partial[bk * 16 + 8 + h];
        const float mn = fmaxf(m, mb);
        l = l * __expf(m - mn) + lb * __expf(mb - mn);
        m = mn;
    }
    __shared__ float rm[256], rl[256];
    rm[t] = m; rl[t] = l;
    __syncthreads();
    for (int s = 128; s >= 8; s >>= 1) {
        if (t < s) {
            const float mo = rm[t + s], lo = rl[t + s];
            const float mn = fmaxf(rm[t], mo);
            rl[t] = rl[t] * __expf(rm[t] - mn) + lo * __expf(mo - mn);
            rm[t] = mn;
        }
        __syncthreads();
    }
    if (t < 8) {
        float gm = gate[0];
        for (int i = 1; i < 8; ++i) gm = fmaxf(gm, gate[i]);
        float gs = 0.f;
        for (int i = 0; i < 8; ++i) gs += __expf(gate[i] - gm);
        const float g = __expf(gate[t] - gm) / gs;
        const float C = g / rl[t];
        coef[t]      = rm[t];
        coef[8 + t]  = C;
        coef[16 + t] = rm[t] + LN_W_EPS - __logf(C);   // t >= cut  <=>  w >= eps
    }
}

// ---------------------------------------------------------------------------
// Mark: recompute t per edge from score gathers, threshold, append passing
// edge ids to elist (wave-aggregated atomic); compact their cols into nlist
// exactly once via atomicExch on colflag.
// ---------------------------------------------------------------------------
__global__ __launch_bounds__(256) void mark_kernel(
    const int* __restrict__ ei, const float* __restrict__ s_src,
    const float* __restrict__ s_dst, const float* __restrict__ coef,
    int* __restrict__ elist, int* __restrict__ colflag,
    int* __restrict__ ecount, int* __restrict__ ncount, int* __restrict__ nlist)
{
    __shared__ float cCut[8];
    if (threadIdx.x < 8) cCut[threadIdx.x] = coef[16 + threadIdx.x];
    __syncthreads();

    const int e = blockIdx.x * 256 + threadIdx.x;
    bool pass = false;
    int col = 0;
    if (e < N_EDGES) {
        const int row = ei[e];
        col = ei[N_EDGES + e];
        const float4 s0 = *(const float4*)(s_src + row * 8);
        const float4 s1 = *(const float4*)(s_src + row * 8 + 4);
        const float4 d0 = *(const float4*)(s_dst + col * 8);
        const float4 d1 = *(const float4*)(s_dst + col * 8 + 4);
        float t[8] = { s0.x + d0.x, s0.y + d0.y, s0.z + d0.z, s0.w + d0.w,
                       s1.x + d1.x, s1.y + d1.y, s1.z + d1.z, s1.w + d1.w };
        #pragma unroll
        for (int h = 0; h < 8; ++h) {
            t[h] = t[h] > 0.f ? t[h] : 0.01f * t[h];
            pass |= (t[h] >= cCut[h]);
        }
    }

    const unsigned long long mask = __ballot(pass);
    if (mask) {
        const int lane   = threadIdx.x & 63;
        const int leader = (int)__builtin_ctzll(mask);
        int base = 0;
        if (lane == leader) base = atomicAdd(ecount, (int)__popcll(mask));
        base = __shfl(base, leader);
        if (pass) {
            const int rank = (int)__popcll(mask & ((1ULL << lane) - 1ULL));
            elist[base + rank] = e;
            if (atomicExch(&colflag[col], 1) == 0) {
                const int ni = atomicAdd(ncount, 1);
                nlist[ni] = col;
            }
        }
    }
}

// ---------------------------------------------------------------------------
// Wh recompute for marked cols only -- SAME verified MFMA bf16x3 block as the
// score GEMM, with row indices indirected through the compacted nlist.
// Grid = 782 blocks, early exit past ncount (~6K marked -> ~100 active).
// Wh stored in the r2-verified PERMUTED layout (element (h,o) at
// h*64 + (o&15)*4 + (o>>4)) so stores are pure float4.
// Worst case (all nodes marked) = one full MFMA GEMM: bounded.
// ---------------------------------------------------------------------------
__global__ __launch_bounds__(512, 2) void whrows_kernel(
    const float* __restrict__ x, const short* __restrict__ wp,
    const float* __restrict__ b, const int* __restrict__ nlist,
    const int* __restrict__ ncount, float* __restrict__ Wh)
{
    __shared__ __align__(16) short As[32768];   // 64 KB
    __shared__ int nl_sh[64];

    const int nc   = *ncount;
    const int row0 = blockIdx.x * 64;
    if (row0 >= nc) return;

    const int tid  = threadIdx.x;
    const int lane = tid & 63;
    const int head = tid >> 6;            // wave == head 0..7
    const int r16  = lane & 15;
    const int kq   = lane >> 4;

    if (tid < 64) {
        const int idx = row0 + tid;
        nl_sh[tid] = (idx < nc) ? nlist[idx] : -1;
    }

    const short* pB = wp + (size_t)kq * 128 + (size_t)r16 * 8;
    #define LD_B2(ni, s, ks) \
        (*(const short8*)(pB + ((((size_t)(head * 4 + (ni)) * 2 + (s)) * 32 + 4 * (ks)) * 128)))
    short8 Bh[2][4], Bl[2][4];
    #pragma unroll
    for (int ni = 0; ni < 4; ++ni) { Bh[0][ni] = LD_B2(ni, 0, 0); Bl[0][ni] = LD_B2(ni, 1, 0); }

    __syncthreads();   // nl_sh visible to fill

    #pragma unroll
    for (int q = 0; q < 4; ++q) {
        const int item = q * 512 + tid;
        const int row  = item >> 5;
        const int kc   = item & 31;
        const int grow = nl_sh[row];
        f32x4 v0 = {0.f, 0.f, 0.f, 0.f}, v1 = {0.f, 0.f, 0.f, 0.f};
        if (grow >= 0) {
            v0 = *(const f32x4*)(x + (size_t)grow * IN_DIM + kc * 8);
            v1 = *(const f32x4*)(x + (size_t)grow * IN_DIM + kc * 8 + 4);
        }
        unsigned hi[4], lo[4];
        bf16_split2(v0.x, v0.y, hi[0], lo[0]);
        bf16_split2(v0.z, v0.w, hi[1], lo[1]);
        bf16_split2(v1.x, v1.y, hi[2], lo[2]);
        bf16_split2(v1.z, v1.w, hi[3], lo[3]);
        const int mi  = row >> 4, rr = row & 15;
        const int swz = rr ^ (kc & 15);
        uint4 vh = make_uint4(hi[0], hi[1], hi[2], hi[3]);
        uint4 vl = make_uint4(lo[0], lo[1], lo[2], lo[3]);
        *(uint4*)((char*)As + ((((mi * 2 + 0) * 32 + kc) * 16 + swz) * 16)) = vh;
        *(uint4*)((char*)As + ((((mi * 2 + 1) * 32 + kc) * 16 + swz) * 16)) = vl;
    }
    __syncthreads();

    f32x4 acc[4][4] = {};

    #define LD_A2(mi, s, ks) \
        (*(const short8*)((const char*)As + \
            (((((mi) * 2 + (s)) * 32 + (4 * (ks) + kq)) * 16 + \
              (r16 ^ ((4 * ((ks) & 3) + kq)))) * 16)))

    short8 Ah[2][4], Al[2][4];
    #pragma unroll
    for (int mi = 0; mi < 4; ++mi) { Ah[0][mi] = LD_A2(mi, 0, 0); Al[0][mi] = LD_A2(mi, 1, 0); }

    #pragma unroll
    for (int ks = 0; ks < 8; ++ks) {
        const int cur = ks & 1, nxt = cur ^ 1;
        if (ks < 7) {
            #pragma unroll
            for (int ni = 0; ni < 4; ++ni) {
                Bh[nxt][ni] = LD_B2(ni, 0, ks + 1);
                Bl[nxt][ni] = LD_B2(ni, 1, ks + 1);
            }
            #pragma unroll
            for (int mi = 0; mi < 4; ++mi) {
                Ah[nxt][mi] = LD_A2(mi, 0, ks + 1);
                Al[nxt][mi] = LD_A2(mi, 1, ks + 1);
            }
        }
        #pragma unroll
        for (int mi = 0; mi < 4; ++mi)
            #pragma unroll
            for (int ni = 0; ni < 4; ++ni) {
                acc[mi][ni] = __builtin_amdgcn_mfma_f32_16x16x32_bf16(
                    Ah[cur][mi], Bh[cur][ni], acc[mi][ni], 0, 0, 0);
                acc[mi][ni] = __builtin_amdgcn_mfma_f32_16x16x32_bf16(
                    Ah[cur][mi], Bl[cur][ni], acc[mi][ni], 0, 0, 0);
                acc[mi][ni] = __builtin_amdgcn_mfma_f32_16x16x32_bf16(
                    Al[cur][mi], Bh[cur][ni], acc[mi][ni], 0, 0, 0);
            }
    }
    #undef LD_A2
    #undef LD_B2

    // epilogue: permuted-layout float4 Wh stores for valid rows
    const int n0 = head * 64;
    float bias[4];
    #pragma unroll
    for (int ni = 0; ni < 4; ++ni) bias[ni] = b[n0 + ni * 16 + r16];

    #pragma unroll
    for (int mi = 0; mi < 4; ++mi) {
        #pragma unroll
        for (int reg = 0; reg < 4; ++reg) {
            const int rloc = mi * 16 + kq * 4 + reg;
            const int n    = nl_sh[rloc];
            if (n >= 0) {
                *(float4*)(Wh + (size_t)n * NCOL + n0 + r16 * 4) =
                    make_float4(acc[mi][0][reg] + bias[0],
                                acc[mi][1][reg] + bias[1],
                                acc[mi][2][reg] + bias[2],
                                acc[mi][3][reg] + bias[3]);
            }
        }
    }
}

// ---------------------------------------------------------------------------
// Accumulate: iterate the compact passing-edge list; recompute w[8] from
// score gathers; wave-cooperative gather of permuted Wh[col]; atomicAdd out.
// ---------------------------------------------------------------------------
__global__ __launch_bounds__(256) void acc_kernel(
    const int* __restrict__ ei, const float* __restrict__ s_src,
    const float* __restrict__ s_dst, const float* __restrict__ Wh,
    const float* __restrict__ coef, const int* __restrict__ elist,
    const int* __restrict__ ecount, float* __restrict__ out)
{
    __shared__ float cM[8], cC[8];
    if (threadIdx.x < 8)       cM[threadIdx.x]     = coef[threadIdx.x];
    else if (threadIdx.x < 16) cC[threadIdx.x - 8] = coef[threadIdx.x];
    __syncthreads();

    const int n    = *ecount;
    const int lane = threadIdx.x & 63;

    for (int i = blockIdx.x * 256 + threadIdx.x; ; i += gridDim.x * 256) {
        const bool has = i < n;
        if (!__any(has)) break;

        int row = 0, col = 0;
        float wgt[8];
        if (has) {
            const int e = elist[i];
            row = ei[e];
            col = ei[N_EDGES + e];
            const float4 s0 = *(const float4*)(s_src + row * 8);
            const float4 s1 = *(const float4*)(s_src + row * 8 + 4);
            const float4 d0 = *(const float4*)(s_dst + col * 8);
            const float4 d1 = *(const float4*)(s_dst + col * 8 + 4);
            float t[8] = { s0.x + d0.x, s0.y + d0.y, s0.z + d0.z, s0.w + d0.w,
                           s1.x + d1.x, s1.y + d1.y, s1.z + d1.z, s1.w + d1.w };
            #pragma unroll
            for (int h = 0; h < 8; ++h) {
                t[h] = t[h] > 0.f ? t[h] : 0.01f * t[h];
                wgt[h] = __expf(t[h] - cM[h]) * cC[h];
            }
        }

        unsigned long long mask = __ballot(has);
        while (mask) {
            const int src = (int)__builtin_ctzll(mask);
            mask &= mask - 1;
            const int rb = __shfl(row, src);
            const int cb = __shfl(col, src);
            // permuted Wh row: element (h, o) at h*64 + (o&15)*4 + (o>>4); o == lane
            const float* wc = Wh + (size_t)cb * NCOL + (lane & 15) * 4 + (lane >> 4);
            float acc = 0.f;
            #pragma unroll
            for (int h = 0; h < 8; ++h)
                acc += __shfl(wgt[h], src) * wc[h * 64];
            atomicAdd(out + (size_t)rb * OUT_DIM + lane, acc);
        }
    }
}

// ---------------------------------------------------------------------------
extern "C" void kernel_launch(void* const* d_in, const int* in_sizes, int n_in,
                              void* d_out, int out_size, void* d_ws, size_t ws_size,
                              hipStream_t stream)
{
    const float* x    = (const float*)d_in[0];
    const int*   ei   = (const int*)  d_in[1];
    const float* W    = (const float*)d_in[2];
    const float* b    = (const float*)d_in[3];
    const float* a    = (const float*)d_in[4];
    const float* gate = (const float*)d_in[5];
    float* out = (float*)d_out;

    // workspace (floats): Wh | s_src | s_dst | partial | coef | wp | elist |
    //                     colflag | ecount | ncount | nlist   (~108 MB)
    float* ws      = (float*)d_ws;
    float* Wh      = ws;
    float* s_src   = Wh    + (size_t)N_NODES * NCOL;
    float* s_dst   = s_src + (size_t)N_NODES * HEADS;
    float* partial = s_dst + (size_t)N_NODES * HEADS;
    float* coef    = partial + (size_t)NBLK_RED * 16;
    short* wp      = (short*)(coef + 32);              // 512 KB, 16B-aligned
    int*   elist   = (int*)(wp + 262144);              // 800K ints
    int*   colflag = elist + N_EDGES;                  // 50K ints
    int*   ecount  = colflag + N_NODES;                // 1 int
    int*   ncount  = ecount + 1;                       // 1 int
    int*   nlist   = ncount + 1;                       // 50K ints

    hipMemsetAsync(d_out, 0, (size_t)N_NODES * OUT_DIM * sizeof(float), stream);
    hipMemsetAsync(colflag, 0, (size_t)(N_NODES + 2) * sizeof(int), stream);

    packw_kernel<<<32, 256, 0, stream>>>(W, wp);

    gemm_kernel<<<(N_NODES + 63) / 64, 512, 0, stream>>>(x, wp, b, a, s_src, s_dst);

    edge_score_kernel<<<NBLK_RED, 256, 0, stream>>>(ei, s_src, s_dst, partial);

    finalize_kernel<<<1, 256, 0, stream>>>(partial, gate, coef, NBLK_RED);

    mark_kernel<<<(N_EDGES + 255) / 256, 256, 0, stream>>>(
        ei, s_src, s_dst, coef, elist, colflag, ecount, ncount, nlist);

    whrows_kernel<<<(N_NODES + 63) / 64, 512, 0, stream>>>(
        x, wp, b, nlist, ncount, Wh);

    acc_kernel<<<256, 256, 0, stream>>>(
        ei, s_src, s_dst, Wh, coef, elist, ecount, out);
}